// Round 4
// baseline (324.421 us; speedup 1.0000x reference)
//
#include <hip/hip_runtime.h>

// RSCA wave-specialized producer/consumer. 512-thread blocks = 8 waves:
// waves 0-3 (t<256) PRODUCE: stream x (13 float4 in flight), pool 7x7 means,
// stage y, per-column minmax partials -> double-buffered LDS slots.
// waves 4-7 (t>=256) CONSUME: 4 scalar-embed MHAs (5.4e8 exp2, trans-bound)
// + residuals, staged to LDS obuf, flushed as aligned float4.
// Handoff: LDS generation counters with __hip_atomic acquire/release
// (workgroup scope) + s_sleep poll — NO __syncthreads in the pipeline, so
// producer memory latency and consumer exp2 issue overlap on every SIMD.
// NG=2 groups/block, grid 1024 (2 blocks/CU = 16 waves/CU): producers never
// block (ready is always signaled), consumers wait only on ready ->
// deadlock-free by construction. Math identical to rounds 0-3 (passed):
// raw-only LDS, k-affine folded into per-query constants, v2f pk math,
// shuffle minmax, XCD-swizzled contiguous columns, obuf float4 flush.

constexpr int B_SEQ = 128;
constexpr int N_COL = 8192;
constexpr int HWP   = 49;
constexpr int NT    = 512;     // 8 waves
constexpr int TC    = 4;       // columns per group
constexpr int NG    = 2;       // groups (pipeline slots) per block
constexpr int CPB   = TC * NG; // 8 columns per block
constexpr int VSTR  = 132;     // LDS value-row stride (16B-aligned rows)
constexpr int OSTR  = 5;       // obuf stride, gcd(5,32)=1

typedef float v2f __attribute__((ext_vector_type(2)));

#if __has_builtin(__builtin_elementwise_fma)
#define VFMA(a, b, c) __builtin_elementwise_fma((a), (b), (c))
#else
__device__ __forceinline__ v2f VFMA(v2f a, v2f b, v2f c) {
    v2f r; r.x = fmaf(a.x, b.x, c.x); r.y = fmaf(a.y, b.y, c.y); return r;
}
#endif

__global__ __launch_bounds__(NT, 4) void rsca_ws(
    const float* __restrict__ x, const float* __restrict__ y,
    const float* __restrict__ pwq, const float* __restrict__ pwk,
    const float* __restrict__ pwv, const float* __restrict__ pbq,
    const float* __restrict__ pbk, const float* __restrict__ pbv,
    const float* __restrict__ pwo, const float* __restrict__ pbo,
    float* __restrict__ out)
{
    __shared__ float kvx[2][TC * VSTR];          // [slot][c*VSTR + j] raw pooled x
    __shared__ float kvy[2][TC * VSTR];          // [slot][c*VSTR + j] raw y
    __shared__ float pmnx[2][8][TC], pmxx[2][8][TC];
    __shared__ float pmny[2][4][TC], pmxy[2][4][TC];
    __shared__ float obuf[2][2][B_SEQ * OSTR];   // [slot][set][i*OSTR + c]
    __shared__ int   rdy[2], dne[2];

    const int t    = threadIdx.x;
    const int bid  = blockIdx.x;
    const int lane = t & 63;
    // XCD-bijective swizzle (grid 1024 % 8 == 0): adjacent column-chunks on
    // one XCD -> L2 write-merge of 64B out lines + y read locality.
    const int cg = (bid & 7) * ((N_COL / CPB) >> 3) + (bid >> 3);
    const int n0 = cg * CPB;

    if (t == 0) { rdy[0] = rdy[1] = 0; dne[0] = dne[1] = 0; }
    __syncthreads();                              // only full barrier (init)

    const float wq = pwq[0], wk = pwk[0], wv = pwv[0];
    const float bq = pbq[0], bk = pbk[0], bv = pbv[0];
    const float wo = pwo[0], bo = pbo[0];
    const float L2E = 1.4426950408889634f;
    const float wkL = wk * L2E, bkL = bk * L2E;
    const float alpha = wo * wv;
    const float beta2 = 2.0f * (wo * bv + bo);

    if (t < 256) {
        // ============================ PRODUCER ============================
        const int ql  = t & 3;
        const int seg = t >> 2;                   // 0..63
        const int wid = t >> 6;                   // 0..3
        for (int g = 0; g < NG; ++g) {
            const int s  = g & 1;
            const int c0 = n0 + g * TC;
            // ---- stage y (raw) + wave-partial minmax ----
            {
                const float fy0 = y[(size_t)seg * N_COL + c0 + ql];
                const float fy1 = y[(size_t)(seg + 64) * N_COL + c0 + ql];
                kvy[s][ql * VSTR + seg]      = fy0;
                kvy[s][ql * VSTR + seg + 64] = fy1;
                float mn = fminf(fy0, fy1), mx = fmaxf(fy0, fy1);
                #pragma unroll
                for (int off = 4; off <= 32; off <<= 1) {
                    mn = fminf(mn, __shfl_xor(mn, off));
                    mx = fmaxf(mx, __shfl_xor(mx, off));
                }
                if (lane < 4) { pmny[s][wid][lane] = mn; pmxy[s][wid][lane] = mx; }
            }
            // ---- pool x (13 float4 in flight per pass) ----
            for (int pass = 0; pass < 2; ++pass) {
                const int j = pass * 64 + seg;
                const float4* __restrict__ base =
                    (const float4*)(x + ((size_t)j * N_COL + c0) * (size_t)HWP);
                float4 v[13];
                #pragma unroll
                for (int k = 0; k < 12; ++k) v[k] = base[ql + 4 * k];
                v[12] = base[48];

                float s0 = 0.f, s1 = 0.f, s2 = 0.f, s3 = 0.f;
                s0 += v[0].x + v[0].y + v[0].z + v[0].w;
                s0 += v[1].x + v[1].y + v[1].z + v[1].w;
                s0 += v[2].x + v[2].y + v[2].z + v[2].w;
                s1 += v[4].x + v[4].y + v[4].z + v[4].w;
                s1 += v[5].x + v[5].y + v[5].z + v[5].w;
                s2 += v[7].x + v[7].y + v[7].z + v[7].w;
                s2 += v[8].x + v[8].y + v[8].z + v[8].w;
                s3 += v[10].x + v[10].y + v[10].z + v[10].w;
                s3 += v[11].x + v[11].y + v[11].z + v[11].w;
                { const float sm = v[3].x + v[3].y + v[3].z + v[3].w;
                  const float cr = (ql == 0) ? v[3].x : 0.0f;
                  s0 += cr; s1 += sm - cr; }
                { const float sm = v[6].x + v[6].y + v[6].z + v[6].w;
                  const float cr = (ql == 0) ? (v[6].x + v[6].y) : 0.0f;
                  s1 += cr; s2 += sm - cr; }
                { const float sm = v[9].x + v[9].y + v[9].z + v[9].w;
                  const float cr = (ql == 0) ? (v[9].x + v[9].y + v[9].z) : 0.0f;
                  s2 += cr; s3 += sm - cr; }
                const float tail = v[12].x + v[12].y + v[12].z + v[12].w;

                s0 += __shfl_xor(s0, 1); s1 += __shfl_xor(s1, 1);
                s2 += __shfl_xor(s2, 1); s3 += __shfl_xor(s3, 1);
                s0 += __shfl_xor(s0, 2); s1 += __shfl_xor(s1, 2);
                s2 += __shfl_xor(s2, 2); s3 += __shfl_xor(s3, 2);
                float r = s0;
                r = (ql == 1) ? s1 : r;
                r = (ql == 2) ? s2 : r;
                r = (ql == 3) ? (s3 + tail) : r;
                const float mean = r * (1.0f / HWP);
                kvx[s][ql * VSTR + j] = mean;

                float mn = mean, mx = mean;
                #pragma unroll
                for (int off = 4; off <= 32; off <<= 1) {
                    mn = fminf(mn, __shfl_xor(mn, off));
                    mx = fmaxf(mx, __shfl_xor(mx, off));
                }
                if (lane < 4) {
                    pmnx[s][pass * 4 + wid][lane] = mn;
                    pmxx[s][pass * 4 + wid][lane] = mx;
                }
            }
            // ---- signal: slot s filled (release orders prior LDS writes) ----
            if (lane == 0)
                __hip_atomic_fetch_add(&rdy[s], 1, __ATOMIC_RELEASE,
                                       __HIP_MEMORY_SCOPE_WORKGROUP);
        }
    } else {
        // ============================ CONSUMER ============================
        const int tc = t - 256;
        const int i  = tc & (B_SEQ - 1);
        const int ch = tc >> 7;                   // 0/1, wave-uniform
        for (int g = 0; g < NG; ++g) {
            const int s   = g & 1;
            const int tgt = 4 * (g / 2 + 1);
            while (__hip_atomic_load(&rdy[s], __ATOMIC_ACQUIRE,
                                     __HIP_MEMORY_SCOPE_WORKGROUP) < tgt)
                __builtin_amdgcn_s_sleep(2);

            #pragma unroll
            for (int cc = 0; cc < 2; ++cc) {
                const int c = ch * 2 + cc;        // wave-uniform -> LDS broadcast
                const float* __restrict__ vx = &kvx[s][c * VSTR];
                const float* __restrict__ vy = &kvy[s][c * VSTR];

                float vxmn = pmnx[s][0][c], vxmx = pmxx[s][0][c];
                #pragma unroll
                for (int p = 1; p < 8; ++p) {
                    vxmn = fminf(vxmn, pmnx[s][p][c]);
                    vxmx = fmaxf(vxmx, pmxx[s][p][c]);
                }
                float vymn = pmny[s][0][c], vymx = pmxy[s][0][c];
                #pragma unroll
                for (int p = 1; p < 4; ++p) {
                    vymn = fminf(vymn, pmny[s][p][c]);
                    vymx = fmaxf(vymx, pmxy[s][p][c]);
                }
                const float axv = fmaf(vxmx, wkL, bkL), bxv = fmaf(vxmn, wkL, bkL);
                const float kxmx = fmaxf(axv, bxv), kxmn = fminf(axv, bxv);
                const float ayv = fmaf(vymx, wkL, bkL), byv = fmaf(vymn, wkL, bkL);
                const float kymx = fmaxf(ayv, byv), kymn = fminf(ayv, byv);

                const float xi = vx[i], yi = vy[i];
                const float qx = fmaf(xi, wq, bq), qy = fmaf(yi, wq, bq);
                const float nmsx = -(qx >= 0.f ? qx * kxmx : qx * kxmn);
                const float nmcy = -(qy >= 0.f ? qy * kxmx : qy * kxmn);
                const float nmsy = -(qy >= 0.f ? qy * kymx : qy * kymn);
                const float nmcx = -(qx >= 0.f ? qx * kymx : qx * kymn);

                // score*log2e = v*(q*wkL) + (q*bkL + nm)
                const float qxw = qx * wkL, qyw = qy * wkL;
                const v2f qxw2 = {qxw, qxw}, qyw2 = {qyw, qyw};
                const float csx = fmaf(qx, bkL, nmsx), ccy = fmaf(qy, bkL, nmcy);
                const float csy = fmaf(qy, bkL, nmsy), ccx = fmaf(qx, bkL, nmcx);
                const v2f csx2 = {csx, csx}, ccy2 = {ccy, ccy};
                const v2f csy2 = {csy, csy}, ccx2 = {ccx, ccx};

                v2f s0sx = {0.f, 0.f}, s1sx = {0.f, 0.f};
                v2f s0cy = {0.f, 0.f}, s1cy = {0.f, 0.f};
                v2f s0sy = {0.f, 0.f}, s1sy = {0.f, 0.f};
                v2f s0cx = {0.f, 0.f}, s1cx = {0.f, 0.f};

                auto px2 = [&](float v0, float v1) {
                    const v2f vvj = {v0, v1};
                    v2f t1 = VFMA(qxw2, vvj, csx2);
                    v2f e1; e1.x = __builtin_amdgcn_exp2f(t1.x);
                            e1.y = __builtin_amdgcn_exp2f(t1.y);
                    s1sx = VFMA(e1, vvj, s1sx); s0sx += e1;
                    v2f t2 = VFMA(qyw2, vvj, ccy2);
                    v2f e2; e2.x = __builtin_amdgcn_exp2f(t2.x);
                            e2.y = __builtin_amdgcn_exp2f(t2.y);
                    s1cy = VFMA(e2, vvj, s1cy); s0cy += e2;
                };
                auto py2 = [&](float v0, float v1) {
                    const v2f vvj = {v0, v1};
                    v2f t3 = VFMA(qyw2, vvj, csy2);
                    v2f e3; e3.x = __builtin_amdgcn_exp2f(t3.x);
                            e3.y = __builtin_amdgcn_exp2f(t3.y);
                    s1sy = VFMA(e3, vvj, s1sy); s0sy += e3;
                    v2f t4 = VFMA(qxw2, vvj, ccx2);
                    v2f e4; e4.x = __builtin_amdgcn_exp2f(t4.x);
                            e4.y = __builtin_amdgcn_exp2f(t4.y);
                    s1cx = VFMA(e4, vvj, s1cx); s0cx += e4;
                };

                // register double-buffer over 8-j chunks
                float4 a0 = *(const float4*)&vx[0], a1 = *(const float4*)&vx[4];
                float4 b0 = *(const float4*)&vy[0], b1 = *(const float4*)&vy[4];
                for (int j0 = 0; j0 < B_SEQ; j0 += 8) {
                    const int jn = (j0 + 8) & (B_SEQ - 1);
                    float4 na0 = *(const float4*)&vx[jn];
                    float4 na1 = *(const float4*)&vx[jn + 4];
                    float4 nb0 = *(const float4*)&vy[jn];
                    float4 nb1 = *(const float4*)&vy[jn + 4];

                    px2(a0.x, a0.y); px2(a0.z, a0.w); px2(a1.x, a1.y); px2(a1.z, a1.w);
                    py2(b0.x, b0.y); py2(b0.z, b0.w); py2(b1.x, b1.y); py2(b1.z, b1.w);

                    a0 = na0; a1 = na1; b0 = nb0; b1 = nb1;
                }
                const float S0sx = s0sx.x + s0sx.y, S1sx = s1sx.x + s1sx.y;
                const float S0cy = s0cy.x + s0cy.y, S1cy = s1cy.x + s1cy.y;
                const float S0sy = s0sy.x + s0sy.y, S1sy = s1sy.x + s1sy.y;
                const float S0cx = s0cx.x + s0cx.y, S1cx = s1cx.x + s1cx.y;
                const float mx_attn = S1sx * __builtin_amdgcn_rcpf(S0sx)
                                    + S1cx * __builtin_amdgcn_rcpf(S0cx);
                const float my_attn = S1sy * __builtin_amdgcn_rcpf(S0sy)
                                    + S1cy * __builtin_amdgcn_rcpf(S0cy);
                obuf[s][0][i * OSTR + c] = fmaf(alpha, mx_attn, beta2 + xi);
                obuf[s][1][i * OSTR + c] = fmaf(alpha, my_attn, beta2 + yi);
            }
            // ---- signal: slot s consumed + obuf[s] written ----
            if (lane == 0)
                __hip_atomic_fetch_add(&dne[s], 1, __ATOMIC_RELEASE,
                                       __HIP_MEMORY_SCOPE_WORKGROUP);
        }
        // ---- final flush: wait all consumer waves, then float4 rows ----
        while (__hip_atomic_load(&dne[0], __ATOMIC_ACQUIRE,
                                 __HIP_MEMORY_SCOPE_WORKGROUP) < 4)
            __builtin_amdgcn_s_sleep(1);
        while (__hip_atomic_load(&dne[1], __ATOMIC_ACQUIRE,
                                 __HIP_MEMORY_SCOPE_WORKGROUP) < 4)
            __builtin_amdgcn_s_sleep(1);
        const int set = tc >> 7;
        const int ii  = tc & (B_SEQ - 1);
        #pragma unroll
        for (int s = 0; s < NG; ++s) {        // slot s holds group s (NG==2)
            const float* p = &obuf[s][set][ii * OSTR];
            float4 val;
            val.x = p[0]; val.y = p[1]; val.z = p[2]; val.w = p[3];
            *(float4*)&out[(size_t)ii * (2 * N_COL) + (size_t)set * N_COL
                           + n0 + s * TC] = val;
        }
    }
}

extern "C" void kernel_launch(void* const* d_in, const int* in_sizes, int n_in,
                              void* d_out, int out_size, void* d_ws, size_t ws_size,
                              hipStream_t stream) {
    const float* x   = (const float*)d_in[0];
    const float* y   = (const float*)d_in[1];
    const float* pwq = (const float*)d_in[2];
    const float* pwk = (const float*)d_in[3];
    const float* pwv = (const float*)d_in[4];
    const float* pbq = (const float*)d_in[5];
    const float* pbk = (const float*)d_in[6];
    const float* pbv = (const float*)d_in[7];
    const float* pwo = (const float*)d_in[8];
    const float* pbo = (const float*)d_in[9];
    float* out = (float*)d_out;

    rsca_ws<<<dim3(N_COL / CPB), dim3(NT), 0, stream>>>(
        x, y, pwq, pwk, pwv, pbq, pbk, pbv, pwo, pbo, out);
}